// Round 1
// baseline (443.742 us; speedup 1.0000x reference)
//
#include <hip/hip_runtime.h>

#define NODES   65536      // B*N
#define NGRAPH  512        // N
#define BATCH   128        // B
#define FIN     75
#define HID     128
#define TOUT    12
#define MAXDEG  10
#define NDEG    11         // degrees 0..10
#define EPSV    1e-5f
#define M_TILE  64
#define MAXT    (NODES / M_TILE)   // 1024 tiles per degree (upper bound)

__device__ __forceinline__ void fma4(float4& a, float s, const float4& w) {
    a.x = fmaf(s, w.x, a.x);
    a.y = fmaf(s, w.y, a.y);
    a.z = fmaf(s, w.z, a.z);
    a.w = fmaf(s, w.w, a.w);
}

// ---------------------------------------------------------------- zero small state
__global__ void k_zero(float* stats1, float* stats2, int* cnt) {
    int t = threadIdx.x;
    if (t < 256) { stats1[t] = 0.f; stats2[t] = 0.f; }
    if (t < 16)  cnt[t] = 0;
}

// ---------------------------------------------------------------- bucket nodes by degree
// Block-local LDS counting, then one global atomicAdd per (block, degree): 2816 atomics total.
__global__ void k_bucket(const int* __restrict__ deg, int* __restrict__ cnt,
                         int* __restrict__ lists) {
    __shared__ int s_cnt[NDEG];
    __shared__ int s_base[NDEG];
    int t = threadIdx.x;
    if (t < NDEG) s_cnt[t] = 0;
    __syncthreads();
    int i = blockIdx.x * 256 + t;
    int d = deg[i];
    d = d < 0 ? 0 : (d > MAXDEG ? MAXDEG : d);
    int pos = atomicAdd(&s_cnt[d], 1);
    __syncthreads();
    if (t < NDEG) s_base[t] = atomicAdd(&cnt[t], s_cnt[t]);
    __syncthreads();
    lists[d * NODES + s_base[d] + pos] = i;
}

// ---------------------------------------------------------------- neighbor sum
// ns[node][f] = sum_{k<deg} src[graph_base + adj[node][k]][f]
template<int F>
__global__ void k_ns(const float* __restrict__ src, const int* __restrict__ adj,
                     const int* __restrict__ deg, float* __restrict__ ns) {
    int e = blockIdx.x * 256 + threadIdx.x;          // < NODES*F (exact grid)
    int node = e / F;
    int f = e - node * F;
    int d = deg[node];
    d = d < 0 ? 0 : (d > MAXDEG ? MAXDEG : d);
    const int* arow = adj + node * MAXDEG;
    int base = (node >> 9) << 9;                     // graph base (N=512)
    float s = 0.f;
    for (int k = 0; k < d; ++k) {
        int a = arow[k];
        s += src[(base + a) * F + f];
    }
    ns[node * F + f] = s;
}

// ---------------------------------------------------------------- per-degree conv GEMM
// Block = (degree d, tile of 64 nodes). Feature rows (self | ns) staged in LDS.
// 256 threads: ng = t>>5 (8 row groups x 8 rows), cg = t&31 (4 cols each).
// Epilogue: write h_out rows + per-block per-feature sum/sumsq partials for BN.
template<int KS>
__global__ __launch_bounds__(256)
void k_conv(const float* __restrict__ selfF, const float* __restrict__ nsF,
            const float* __restrict__ Wself, const float* __restrict__ Wneigh,
            const float* __restrict__ bself, const float* __restrict__ bneigh,
            const int* __restrict__ lists, const int* __restrict__ cnt,
            float* __restrict__ out, float* __restrict__ partials) {
    constexpr int K    = 2 * KS;
    constexpr int SOFF = (KS == 75) ? 76 : 128;   // 16B-aligned neighbor segment
    constexpr int FSTR = (KS == 75) ? 152 : 256;  // LDS row stride (floats)

    __shared__ int   s_ids[M_TILE];
    __shared__ float s_feat[M_TILE * FSTR];

    const int d  = blockIdx.y;
    const int c  = cnt[d];
    const int m0 = blockIdx.x * M_TILE;
    if (m0 >= c) return;
    const int mv = min(M_TILE, c - m0);
    const int t  = threadIdx.x;

    if (t < M_TILE) s_ids[t] = (t < mv) ? lists[d * NODES + m0 + t] : -1;
    __syncthreads();

    // stage features: [self(KS) | pad | ns(KS)]
    for (int e = t; e < M_TILE * K; e += 256) {
        int i = e / K;
        int k = e - i * K;
        int id = s_ids[i];
        float v = 0.f;
        if (id >= 0) v = (k < KS) ? selfF[id * KS + k] : nsF[id * KS + (k - KS)];
        int col = (k < KS) ? k : (k - KS + SOFF);
        s_feat[i * FSTR + col] = v;
    }
    __syncthreads();

    const int cg = t & 31;
    const int ng = t >> 5;
    const float* frow = s_feat + (ng * 8) * FSTR;

    float4 acc[8];
    {
        float4 bias = *(const float4*)(bself + d * HID + cg * 4);
        if (d > 0) {
            float4 bn = *(const float4*)(bneigh + (d - 1) * HID + cg * 4);
            bias.x += bn.x; bias.y += bn.y; bias.z += bn.z; bias.w += bn.w;
        }
        #pragma unroll
        for (int j = 0; j < 8; ++j) acc[j] = bias;
    }

    auto seg = [&](const float* W, int soff) {
        constexpr int K4 = KS / 4;
        for (int k4 = 0; k4 < K4; ++k4) {
            float4 fv[8];
            #pragma unroll
            for (int j = 0; j < 8; ++j)
                fv[j] = *(const float4*)(frow + j * FSTR + soff + k4 * 4);
            const float* wp = W + (k4 * 4) * HID + cg * 4;
            float4 w0 = *(const float4*)(wp);
            float4 w1 = *(const float4*)(wp + HID);
            float4 w2 = *(const float4*)(wp + 2 * HID);
            float4 w3 = *(const float4*)(wp + 3 * HID);
            #pragma unroll
            for (int j = 0; j < 8; ++j) {
                fma4(acc[j], fv[j].x, w0);
                fma4(acc[j], fv[j].y, w1);
                fma4(acc[j], fv[j].z, w2);
                fma4(acc[j], fv[j].w, w3);
            }
        }
        if constexpr ((KS % 4) != 0) {
            for (int k = K4 * 4; k < KS; ++k) {
                float4 w = *(const float4*)(W + k * HID + cg * 4);
                #pragma unroll
                for (int j = 0; j < 8; ++j)
                    fma4(acc[j], frow[j * FSTR + soff + k], w);
            }
        }
    };

    seg(Wself + d * KS * HID, 0);
    if (d > 0) seg(Wneigh + (d - 1) * KS * HID, SOFF);

    // epilogue: store rows + per-column partial sum/sumsq (valid rows only)
    float4 csum = make_float4(0.f, 0.f, 0.f, 0.f);
    float4 csq  = make_float4(0.f, 0.f, 0.f, 0.f);
    #pragma unroll
    for (int j = 0; j < 8; ++j) {
        int i = ng * 8 + j;
        if (i < mv) {
            *(float4*)(out + s_ids[i] * HID + cg * 4) = acc[j];
            csum.x += acc[j].x; csum.y += acc[j].y; csum.z += acc[j].z; csum.w += acc[j].w;
            csq.x += acc[j].x * acc[j].x; csq.y += acc[j].y * acc[j].y;
            csq.z += acc[j].z * acc[j].z; csq.w += acc[j].w * acc[j].w;
        }
    }
    __syncthreads();                      // safe to reuse s_feat
    float* s_red = s_feat;                // [8][256]
    s_red[ng * 256 + cg * 4 + 0] = csum.x;
    s_red[ng * 256 + cg * 4 + 1] = csum.y;
    s_red[ng * 256 + cg * 4 + 2] = csum.z;
    s_red[ng * 256 + cg * 4 + 3] = csum.w;
    s_red[ng * 256 + 128 + cg * 4 + 0] = csq.x;
    s_red[ng * 256 + 128 + cg * 4 + 1] = csq.y;
    s_red[ng * 256 + 128 + cg * 4 + 2] = csq.z;
    s_red[ng * 256 + 128 + cg * 4 + 3] = csq.w;
    __syncthreads();
    float tot = 0.f;
    #pragma unroll
    for (int g = 0; g < 8; ++g) tot += s_red[g * 256 + t];
    partials[(d * MAXT + blockIdx.x) * 256 + t] = tot;
}

// ---------------------------------------------------------------- reduce BN partials
__global__ void k_redstats(const float* __restrict__ partials, const int* __restrict__ cnt,
                           float* __restrict__ stats) {
    int t = threadIdx.x;   // 256: 0..127 sum, 128..255 sumsq
    float acc = 0.f;
    for (int d = 0; d < NDEG; ++d) {
        int nt = (cnt[d] + M_TILE - 1) / M_TILE;
        for (int tile = blockIdx.x; tile < nt; tile += gridDim.x)
            acc += partials[(d * MAXT + tile) * 256 + t];
    }
    atomicAdd(&stats[t], acc);
}

// ---------------------------------------------------------------- BN + ReLU in place
__global__ void k_bnrelu(float* __restrict__ h, const float* __restrict__ stats,
                         const float* __restrict__ gamma, const float* __restrict__ beta) {
    int idx = blockIdx.x * 256 + threadIdx.x;    // < NODES*HID/4 (exact grid)
    int h0 = (idx * 4) & (HID - 1);
    float4 v = *(float4*)(h + idx * 4);
    const float inv = 1.f / (float)NODES;
    float* vp = (float*)&v;
    #pragma unroll
    for (int j = 0; j < 4; ++j) {
        int col = h0 + j;
        float mu  = stats[col] * inv;
        float var = stats[HID + col] * inv - mu * mu;
        float rs  = rsqrtf(var + EPSV);
        float sc  = gamma[col] * rs;
        float sh  = beta[col] - mu * sc;
        vp[j] = fmaxf(fmaf(vp[j], sc, sh), 0.f);
    }
    *(float4*)(h + idx * 4) = v;
}

// ---------------------------------------------------------------- BN2 + ReLU + mean over N + dense
__global__ void k_pool_dense(const float* __restrict__ h2, const float* __restrict__ stats,
                             const float* __restrict__ gamma, const float* __restrict__ beta,
                             const float* __restrict__ Wd, const float* __restrict__ bd,
                             float* __restrict__ outp) {
    __shared__ float s_part[4][HID];
    __shared__ float s_pool[HID];
    const int b = blockIdx.x;
    const int t = threadIdx.x;        // 512
    const int hcol = t & (HID - 1);
    const int q = t >> 7;             // 0..3
    const float inv = 1.f / (float)NODES;
    float mu  = stats[hcol] * inv;
    float var = stats[HID + hcol] * inv - mu * mu;
    float rs  = rsqrtf(var + EPSV);
    float sc  = gamma[hcol] * rs;
    float sh  = beta[hcol] - mu * sc;
    float acc = 0.f;
    const float* hp = h2 + (b * NGRAPH + q * 128) * HID + hcol;
    #pragma unroll 4
    for (int n = 0; n < 128; ++n)
        acc += fmaxf(fmaf(hp[n * HID], sc, sh), 0.f);
    s_part[q][hcol] = acc;
    __syncthreads();
    if (t < HID)
        s_pool[t] = (s_part[0][t] + s_part[1][t] + s_part[2][t] + s_part[3][t]) * (1.f / NGRAPH);
    __syncthreads();
    if (t < TOUT) {
        float o = bd[t];
        for (int hh = 0; hh < HID; ++hh)
            o = fmaf(s_pool[hh], Wd[hh * TOUT + t], o);
        outp[b * TOUT + t] = o;
    }
}

// ---------------------------------------------------------------- launch
extern "C" void kernel_launch(void* const* d_in, const int* in_sizes, int n_in,
                              void* d_out, int out_size, void* d_ws, size_t ws_size,
                              hipStream_t stream) {
    const float* x   = (const float*)d_in[0];
    const int*   adj = (const int*)d_in[1];
    const int*   deg = (const int*)d_in[2];
    const float* Wn1 = (const float*)d_in[3];
    const float* Ws1 = (const float*)d_in[4];
    const float* bn1 = (const float*)d_in[5];
    const float* bs1 = (const float*)d_in[6];
    const float* g1  = (const float*)d_in[7];
    const float* be1 = (const float*)d_in[8];
    const float* Wn2 = (const float*)d_in[9];
    const float* Ws2 = (const float*)d_in[10];
    const float* bn2 = (const float*)d_in[11];
    const float* bs2 = (const float*)d_in[12];
    const float* g2  = (const float*)d_in[13];
    const float* be2 = (const float*)d_in[14];
    const float* Wd  = (const float*)d_in[15];
    const float* bd  = (const float*)d_in[16];

    float* ws     = (float*)d_ws;
    float* h1     = ws;                       // NODES*HID           = 8388608 f
    float* h2     = h1 + NODES * HID;         // NODES*HID
    float* nsb    = h2 + NODES * HID;         // NODES*HID (layer1 uses NODES*75 of it)
    float* part   = nsb + NODES * HID;        // NDEG*MAXT*256       = 2883584 f
    float* stats1 = part + NDEG * MAXT * 256; // 256
    float* stats2 = stats1 + 256;             // 256
    int*   cnt    = (int*)(stats2 + 256);     // 16
    int*   lists  = cnt + 16;                 // NDEG*NODES ints
    // total ~115 MB

    k_zero<<<1, 256, 0, stream>>>(stats1, stats2, cnt);
    k_bucket<<<NODES / 256, 256, 0, stream>>>(deg, cnt, lists);

    // ----- layer 1
    k_ns<FIN><<<NODES * FIN / 256, 256, 0, stream>>>(x, adj, deg, nsb);
    k_conv<FIN><<<dim3(MAXT, NDEG), 256, 0, stream>>>(x, nsb, Ws1, Wn1, bs1, bn1,
                                                      lists, cnt, h1, part);
    k_redstats<<<32, 256, 0, stream>>>(part, cnt, stats1);
    k_bnrelu<<<NODES * HID / 4 / 256, 256, 0, stream>>>(h1, stats1, g1, be1);

    // ----- layer 2
    k_ns<HID><<<NODES * HID / 256, 256, 0, stream>>>(h1, adj, deg, nsb);
    k_conv<HID><<<dim3(MAXT, NDEG), 256, 0, stream>>>(h1, nsb, Ws2, Wn2, bs2, bn2,
                                                      lists, cnt, h2, part);
    k_redstats<<<32, 256, 0, stream>>>(part, cnt, stats2);

    // ----- BN2 + ReLU + pool + dense
    k_pool_dense<<<BATCH, 512, 0, stream>>>(h2, stats2, g2, be2, Wd, bd, (float*)d_out);
}